// Round 6
// baseline (141.794 us; speedup 1.0000x reference)
//
#include <hip/hip_runtime.h>
#include <math.h>

#define HIDDEN 200
#define LOG2E 1.4426950408889634f
#define LN2   0.6931471805599453f

typedef float f32x4 __attribute__((ext_vector_type(4)));

// ---------------------------------------------------------------------------
// Kernel 1: build merged per-entity / per-relation tables.
//   EA[e][0..199]   = exp(ent[e,:] @ g_w[0:200,:])           (pre-exp'd g)
//   EA[e][200..399] =     ent[e,:] @ c_w[0:200,:]            (raw c)
//   EB[r][0..199]   = exp(rel[r,:] @ g_w[200:400,:] + tim @ g_w[400:600,:] + g_b)
//   EB[r][200..399] =     rel[r,:] @ c_w[200:400,:] + tim @ c_w[400:600,:] + c_b
// ---------------------------------------------------------------------------
__global__ __launch_bounds__(256) void precompute_kernel(
    const float* __restrict__ ent, const float* __restrict__ rel,
    const float* __restrict__ tim,
    const float* __restrict__ g_w, const float* __restrict__ g_b,
    const float* __restrict__ c_w, const float* __restrict__ c_b,
    float* __restrict__ EA, float* __restrict__ EB) {
  const int mode = blockIdx.y;  // 0 = g (exp'd), 1 = c (raw)
  const float* w = mode ? c_w : g_w;
  const float* bias = mode ? c_b : g_b;
  const bool is_ent = blockIdx.x < 500;
  const int row0 = is_ent ? blockIdx.x * 2 : (blockIdx.x - 500) * 2;
  const float* in = is_ent ? ent : rel;
  const int k0 = is_ent ? 0 : 200;
  float* obase = is_ent ? (EA + row0 * 400 + mode * 200)
                        : (EB + row0 * 400 + mode * 200);

  __shared__ float a0[HIDDEN], a1[HIDDEN], tl[HIDDEN];
  const int c = threadIdx.x;
  if (c < HIDDEN) {
    a0[c] = in[row0 * HIDDEN + c];
    a1[c] = in[(row0 + 1) * HIDDEN + c];
    if (!is_ent) tl[c] = tim[c];
  }
  __syncthreads();
  if (c >= HIDDEN) return;

  const float* wp = w + k0 * HIDDEN + c;
  float acc0a = 0.f, acc0b = 0.f, acc1a = 0.f, acc1b = 0.f;
  #pragma unroll 4
  for (int k = 0; k < 100; ++k) {
    float w0 = wp[k * HIDDEN];
    float w1 = wp[(k + 100) * HIDDEN];
    acc0a += a0[k] * w0;
    acc0b += a0[k + 100] * w1;
    acc1a += a1[k] * w0;
    acc1b += a1[k + 100] * w1;
  }
  float r0 = acc0a + acc0b;
  float r1 = acc1a + acc1b;
  if (!is_ent) {
    const float* wt = w + 400 * HIDDEN + c;
    float ta = 0.f, tb = 0.f;
    #pragma unroll 4
    for (int k = 0; k < 100; ++k) {
      ta += tl[k] * wt[k * HIDDEN];
      tb += tl[k + 100] * wt[(k + 100) * HIDDEN];
    }
    float extra = ta + tb + bias[c];
    r0 += extra;
    r1 += extra;
  }
  if (mode == 0) {
    r0 = __builtin_amdgcn_exp2f(r0 * LOG2E);
    r1 = __builtin_amdgcn_exp2f(r1 * LOG2E);
  }
  obase[c] = r0;
  obase[400 + c] = r1;
}

// ---------------------------------------------------------------------------
// Kernel 2: pair-denominator tables over ALL (s,r) pairs (only 1000x100):
//   SG[s][r] = sum_j EAg[s][j]*EBg[r][j]          (softmax-g denominator)
//   SC[s][r] = sum_j exp(tanh(Ac[s][j]+Bc[r][j])) (softmax-c denominator)
// One block per s; thread r walks the 200 columns. EB is L2-resident and
// column-line reuse (16 consecutive k per 64B line) keeps L1 happy.
// ---------------------------------------------------------------------------
__global__ __launch_bounds__(128) void pair_kernel(
    const float* __restrict__ EA, const float* __restrict__ EB,
    float* __restrict__ SG, float* __restrict__ SC) {
  const int s = blockIdx.x;
  __shared__ float row[400];  // [0..200)=EAg[s], [200..400)=Ac[s]
  for (int i = threadIdx.x; i < 400; i += 128) row[i] = EA[s * 400 + i];
  __syncthreads();
  const int r = threadIdx.x;
  if (r >= 100) return;

  const float* ebg = EB + r * 400;
  const float* ebc = ebg + 200;
  float sg = 0.f, sc = 0.f;
  #pragma unroll 4
  for (int k = 0; k < 200; ++k) {
    sg = fmaf(row[k], ebg[k], sg);
    float x = row[200 + k] + ebc[k];
    float e2 = __builtin_amdgcn_exp2f(x * (2.f * LOG2E));
    float th = (e2 - 1.f) * __builtin_amdgcn_rcpf(e2 + 1.f);
    sc += __builtin_amdgcn_exp2f(th * LOG2E);
  }
  SG[s * 100 + r] = sg;
  SC[s * 100 + r] = sc;
}

// ---------------------------------------------------------------------------
// Kernel 3: fully thread-parallel query evaluation. Thread t -> query q=t/50,
// column-quad j=t%50. No cross-lane ops, no idle lanes; stores are globally
// contiguous f32x4. History copy-mask cancels under softmax shift-invariance
// (per-row constant on every logit) -> history arrays never read. Logits are
// bounded (|x|<~0.5) so no max-subtraction is needed.
//   out = log(eg/(2 SG) + ec/(2 SC))
// ---------------------------------------------------------------------------
__global__ __launch_bounds__(256) void query_kernel(
    const float* __restrict__ EA, const float* __restrict__ EB,
    const float* __restrict__ SG, const float* __restrict__ SC,
    const int* __restrict__ sub, const int* __restrict__ rel,
    float* __restrict__ out, int total) {
  int t = blockIdx.x * blockDim.x + threadIdx.x;
  if (t >= total) return;
  unsigned q = (unsigned)t / 50u;
  unsigned j = (unsigned)t - q * 50u;

  int s = sub[q];
  int r = rel[q];
  float isg = 0.5f * __builtin_amdgcn_rcpf(SG[s * 100 + r]);
  float isc = 0.5f * __builtin_amdgcn_rcpf(SC[s * 100 + r]);

  const f32x4* ea = (const f32x4*)(EA + s * 400);
  const f32x4* eb = (const f32x4*)(EB + r * 400);
  f32x4 eg = ea[j] * eb[j];
  f32x4 xc = ea[j + 50] + eb[j + 50];

  f32x4 o;
  #pragma unroll
  for (int i = 0; i < 4; ++i) {
    float e2 = __builtin_amdgcn_exp2f(xc[i] * (2.f * LOG2E));
    float th = (e2 - 1.f) * __builtin_amdgcn_rcpf(e2 + 1.f);
    float ec = __builtin_amdgcn_exp2f(th * LOG2E);
    float v = fmaf(eg[i], isg, ec * isc);
    o[i] = __builtin_amdgcn_logf(v) * LN2;
  }
  __builtin_nontemporal_store(o, (f32x4*)out + t);
}

// ---------------------------------------------------------------------------
extern "C" void kernel_launch(void* const* d_in, const int* in_sizes, int n_in,
                              void* d_out, int out_size, void* d_ws, size_t ws_size,
                              hipStream_t stream) {
  const float* ent  = (const float*)d_in[0];
  const float* relE = (const float*)d_in[1];
  const float* tim  = (const float*)d_in[2];
  const float* g_w  = (const float*)d_in[3];
  const float* g_b  = (const float*)d_in[4];
  const float* c_w  = (const float*)d_in[5];
  const float* c_b  = (const float*)d_in[6];
  // d_in[7..9] (history) are mathematically dead: the copy-mask is a per-row
  // constant added to every softmax logit, which cancels exactly.
  const int* sub = (const int*)d_in[10];
  const int* rel = (const int*)d_in[11];
  float* out = (float*)d_out;
  int N = in_sizes[10];

  float* ws = (float*)d_ws;
  float* EA = ws;            // 1000 * 400
  float* EB = ws + 400000;   // 100 * 400
  float* SG = ws + 440000;   // 1000 * 100
  float* SC = ws + 540000;   // 1000 * 100

  dim3 grid1(550, 2);
  precompute_kernel<<<grid1, 256, 0, stream>>>(ent, relE, tim, g_w, g_b, c_w,
                                               c_b, EA, EB);
  pair_kernel<<<1000, 128, 0, stream>>>(EA, EB, SG, SC);

  int total = N * 50;  // one thread per 4 output columns
  int blocks = (total + 255) / 256;
  query_kernel<<<blocks, 256, 0, stream>>>(EA, EB, SG, SC, sub, rel, out,
                                           total);
}

// Round 7
// 138.396 us; speedup vs baseline: 1.0246x; 1.0246x over previous
//
#include <hip/hip_runtime.h>
#include <math.h>

#define HIDDEN 200
#define LOG2E 1.4426950408889634f
#define LN2   0.6931471805599453f

typedef float f32x4 __attribute__((ext_vector_type(4)));

// ---------------------------------------------------------------------------
// Kernel 1: build merged per-entity / per-relation tables.
//   EA[e][0..199]   = exp(ent[e,:] @ g_w[0:200,:])           (pre-exp'd g)
//   EA[e][200..399] =     ent[e,:] @ c_w[0:200,:]            (raw c)
//   EB[r][0..199]   = exp(rel[r,:] @ g_w[200:400,:] + tim @ g_w[400:600,:] + g_b)
//   EB[r][200..399] =     rel[r,:] @ c_w[200:400,:] + tim @ c_w[400:600,:] + c_b
// Also writes EBt[col][r] (transpose) so pair_kernel's lane-r access is
// coalesced (lanes contiguous). 40K scattered stores, negligible.
// ---------------------------------------------------------------------------
__global__ __launch_bounds__(256) void precompute_kernel(
    const float* __restrict__ ent, const float* __restrict__ rel,
    const float* __restrict__ tim,
    const float* __restrict__ g_w, const float* __restrict__ g_b,
    const float* __restrict__ c_w, const float* __restrict__ c_b,
    float* __restrict__ EA, float* __restrict__ EB,
    float* __restrict__ EBt) {
  const int mode = blockIdx.y;  // 0 = g (exp'd), 1 = c (raw)
  const float* w = mode ? c_w : g_w;
  const float* bias = mode ? c_b : g_b;
  const bool is_ent = blockIdx.x < 500;
  const int row0 = is_ent ? blockIdx.x * 2 : (blockIdx.x - 500) * 2;
  const float* in = is_ent ? ent : rel;
  const int k0 = is_ent ? 0 : 200;

  __shared__ float a0[HIDDEN], a1[HIDDEN], tl[HIDDEN];
  const int c = threadIdx.x;
  if (c < HIDDEN) {
    a0[c] = in[row0 * HIDDEN + c];
    a1[c] = in[(row0 + 1) * HIDDEN + c];
    if (!is_ent) tl[c] = tim[c];
  }
  __syncthreads();
  if (c >= HIDDEN) return;

  const float* wp = w + k0 * HIDDEN + c;
  float acc0a = 0.f, acc0b = 0.f, acc1a = 0.f, acc1b = 0.f;
  #pragma unroll 4
  for (int k = 0; k < 100; ++k) {
    float w0 = wp[k * HIDDEN];
    float w1 = wp[(k + 100) * HIDDEN];
    acc0a += a0[k] * w0;
    acc0b += a0[k + 100] * w1;
    acc1a += a1[k] * w0;
    acc1b += a1[k + 100] * w1;
  }
  float r0 = acc0a + acc0b;
  float r1 = acc1a + acc1b;
  if (!is_ent) {
    const float* wt = w + 400 * HIDDEN + c;
    float ta = 0.f, tb = 0.f;
    #pragma unroll 4
    for (int k = 0; k < 100; ++k) {
      ta += tl[k] * wt[k * HIDDEN];
      tb += tl[k + 100] * wt[(k + 100) * HIDDEN];
    }
    float extra = ta + tb + bias[c];
    r0 += extra;
    r1 += extra;
  }
  if (mode == 0) {
    r0 = __builtin_amdgcn_exp2f(r0 * LOG2E);
    r1 = __builtin_amdgcn_exp2f(r1 * LOG2E);
  }
  const int col = mode * 200 + c;
  if (is_ent) {
    EA[row0 * 400 + col] = r0;
    EA[(row0 + 1) * 400 + col] = r1;
  } else {
    EB[row0 * 400 + col] = r0;
    EB[(row0 + 1) * 400 + col] = r1;
    EBt[col * 100 + row0] = r0;       // transpose copy for pair_kernel
    EBt[col * 100 + row0 + 1] = r1;
  }
}

// ---------------------------------------------------------------------------
// Kernel 2: pair-denominator tables over all (s,r) pairs (1000 x 100):
//   SG[s][r] = sum_k EAg[s][k]*EBg[r][k]
//   SC[s][r] = sum_k exp(tanh(Ac[s][k]+Bc[r][k]))
// Block per s, 256 threads = (half, r): half-split over k for 2x waves and
// half the serial chain; EBt[k*100+r] gives contiguous lane addresses
// (coalesced, 2 lines/wave-load instead of 64 in the R6 version).
// ---------------------------------------------------------------------------
__global__ __launch_bounds__(256) void pair_kernel(
    const float* __restrict__ EA, const float* __restrict__ EBt,
    float* __restrict__ SG, float* __restrict__ SC) {
  const int s = blockIdx.x;
  __shared__ float row[400];  // [0..200)=EAg[s], [200..400)=Ac[s]
  __shared__ float psg[256], psc[256];
  const int tid = threadIdx.x;
  for (int i = tid; i < 400; i += 256) row[i] = EA[s * 400 + i];
  __syncthreads();

  const int half = tid >> 7;        // 0 or 1
  const int r = tid & 127;          // 0..127, active < 100
  float sg = 0.f, sc = 0.f;
  if (r < 100) {
    const int kbase = half * 100;
    const float* tg = EBt + kbase * 100 + r;          // g rows [kbase..)
    const float* tc = EBt + (200 + kbase) * 100 + r;  // c rows
    #pragma unroll 4
    for (int k = 0; k < 100; ++k) {
      sg = fmaf(row[kbase + k], tg[k * 100], sg);
      float x = row[200 + kbase + k] + tc[k * 100];
      float e2 = __builtin_amdgcn_exp2f(x * (2.f * LOG2E));
      float th = (e2 - 1.f) * __builtin_amdgcn_rcpf(e2 + 1.f);
      sc += __builtin_amdgcn_exp2f(th * LOG2E);
    }
  }
  psg[tid] = sg;
  psc[tid] = sc;
  __syncthreads();
  if (half == 0 && r < 100) {
    SG[s * 100 + r] = psg[r] + psg[r + 128];
    SC[s * 100 + r] = psc[r] + psc[r + 128];
  }
}

// ---------------------------------------------------------------------------
// Kernel 3: fully thread-parallel query evaluation. Thread t -> query q=t/50,
// column-quad j=t%50. No cross-lane ops, no idle lanes; stores are globally
// contiguous f32x4. History copy-mask cancels under softmax shift-invariance
// (per-row constant on every logit) -> history arrays never read. Logits are
// bounded (|x|<~0.5) so no max-subtraction is needed.
//   out = log(eg/(2 SG) + ec/(2 SC))
// ---------------------------------------------------------------------------
__global__ __launch_bounds__(256) void query_kernel(
    const float* __restrict__ EA, const float* __restrict__ EB,
    const float* __restrict__ SG, const float* __restrict__ SC,
    const int* __restrict__ sub, const int* __restrict__ rel,
    float* __restrict__ out, int total) {
  int t = blockIdx.x * blockDim.x + threadIdx.x;
  if (t >= total) return;
  unsigned q = (unsigned)t / 50u;
  unsigned j = (unsigned)t - q * 50u;

  int s = sub[q];
  int r = rel[q];
  float isg = 0.5f * __builtin_amdgcn_rcpf(SG[s * 100 + r]);
  float isc = 0.5f * __builtin_amdgcn_rcpf(SC[s * 100 + r]);

  const f32x4* ea = (const f32x4*)(EA + s * 400);
  const f32x4* eb = (const f32x4*)(EB + r * 400);
  f32x4 eg = ea[j] * eb[j];
  f32x4 xc = ea[j + 50] + eb[j + 50];

  f32x4 o;
  #pragma unroll
  for (int i = 0; i < 4; ++i) {
    float e2 = __builtin_amdgcn_exp2f(xc[i] * (2.f * LOG2E));
    float th = (e2 - 1.f) * __builtin_amdgcn_rcpf(e2 + 1.f);
    float ec = __builtin_amdgcn_exp2f(th * LOG2E);
    float v = fmaf(eg[i], isg, ec * isc);
    o[i] = __builtin_amdgcn_logf(v) * LN2;
  }
  __builtin_nontemporal_store(o, (f32x4*)out + t);
}

// ---------------------------------------------------------------------------
extern "C" void kernel_launch(void* const* d_in, const int* in_sizes, int n_in,
                              void* d_out, int out_size, void* d_ws, size_t ws_size,
                              hipStream_t stream) {
  const float* ent  = (const float*)d_in[0];
  const float* relE = (const float*)d_in[1];
  const float* tim  = (const float*)d_in[2];
  const float* g_w  = (const float*)d_in[3];
  const float* g_b  = (const float*)d_in[4];
  const float* c_w  = (const float*)d_in[5];
  const float* c_b  = (const float*)d_in[6];
  // d_in[7..9] (history) are mathematically dead: the copy-mask is a per-row
  // constant added to every softmax logit, which cancels exactly.
  const int* sub = (const int*)d_in[10];
  const int* rel = (const int*)d_in[11];
  float* out = (float*)d_out;
  int N = in_sizes[10];

  float* ws = (float*)d_ws;
  float* EA  = ws;            // 1000 * 400
  float* EB  = ws + 400000;   // 100 * 400
  float* EBt = ws + 440000;   // 400 * 100
  float* SG  = ws + 480000;   // 1000 * 100
  float* SC  = ws + 580000;   // 1000 * 100

  dim3 grid1(550, 2);
  precompute_kernel<<<grid1, 256, 0, stream>>>(ent, relE, tim, g_w, g_b, c_w,
                                               c_b, EA, EB, EBt);
  pair_kernel<<<1000, 256, 0, stream>>>(EA, EBt, SG, SC);

  int total = N * 50;  // one thread per 4 output columns
  int blocks = (total + 255) / 256;
  query_kernel<<<blocks, 256, 0, stream>>>(EA, EB, SG, SC, sub, rel, out,
                                           total);
}